// Round 2
// baseline (455.750 us; speedup 1.0000x reference)
//
#include <hip/hip_runtime.h>

#define EPROJS 1024
#define DUNITS 1024
#define AHEADS 4
#define DK 512
#define DV 512
#define CCH 128
#define BB 16
#define TT 2048

typedef __attribute__((ext_vector_type(8))) short bf16x8;
typedef __attribute__((ext_vector_type(4))) float f32x4;

static __device__ __forceinline__ short f2bf(float x) {
  unsigned u = __float_as_uint(x);
  unsigned r = u + 0x7fffu + ((u >> 16) & 1u);   // RNE to bf16 (inputs finite)
  return (short)(r >> 16);
}

static __device__ __forceinline__ float fast_tanh(float x) {
  float e2 = __expf(2.0f * x);
  return 1.0f - 2.0f / (e2 + 1.0f);   // safe at +-inf of e2
}

// ---------- f32 -> bf16 conversion (vector of 4) ----------
__global__ __launch_bounds__(256) void cvt_kernel(const float* __restrict__ in,
                                                  short* __restrict__ out, int n4) {
  int i = blockIdx.x * blockDim.x + threadIdx.x;
  if (i >= n4) return;
  float4 v = reinterpret_cast<const float4*>(in)[i];
  short4 o;
  o.x = f2bf(v.x); o.y = f2bf(v.y); o.z = f2bf(v.z); o.w = f2bf(v.w);
  reinterpret_cast<short4*>(out)[i] = o;
}

// ---------- filter prefix sums: S[h][tau][c], tau in [0, L] ----------
__global__ __launch_bounds__(128) void prefix_kernel(const float* __restrict__ w0,
                                                     const float* __restrict__ w1,
                                                     const float* __restrict__ w2,
                                                     const float* __restrict__ w3,
                                                     float* __restrict__ S) {
  int h = blockIdx.x, c = threadIdx.x;
  const float* wk = (h == 0) ? w0 : (h == 1) ? w1 : (h == 2) ? w2 : w3;
  int af = (100 * (h + 1)) >> 2;
  int L = 2 * af + 1;
  float* Sh = S + h * 202 * 128;
  float s = 0.f;
  Sh[c] = 0.f;
  for (int t = 0; t < L; ++t) { s += wk[c * L + t]; Sh[(t + 1) * 128 + c] = s; }
}

// ---------- Q[h][b][k] = dec_z[b] . Wq[h][k] + bq[h][k], one wave per output ----------
__global__ __launch_bounds__(256) void q_kernel(const float* __restrict__ dec,
                                                const float* __restrict__ Wq,
                                                const float* __restrict__ bq,
                                                float* __restrict__ Qb) {
  int wid = (blockIdx.x * blockDim.x + threadIdx.x) >> 6;
  int lane = threadIdx.x & 63;
  int k = wid & (DK - 1); int hb = wid >> 9; int b = hb & (BB - 1); int h = hb >> 4;
  const float4* d4 = reinterpret_cast<const float4*>(dec + b * DUNITS);
  const float4* w4 = reinterpret_cast<const float4*>(Wq + (size_t)(h * DK + k) * DUNITS);
  float s = 0.f;
#pragma unroll
  for (int j = 0; j < 4; ++j) {
    float4 a = d4[j * 64 + lane], w = w4[j * 64 + lane];
    s += a.x * w.x + a.y * w.y + a.z * w.z + a.w * w.w;
  }
#pragma unroll
  for (int off = 32; off; off >>= 1) s += __shfl_xor(s, off);
  if (lane == 0) Qb[wid] = s + bq[h * DK + k];
}

// ---------- fused e kernel: e[h][b][t] = sum_k tanh(enc.Wk^T + conv.Watt^T + Q) * g_w + g_b
// bf16 enc input; double-buffered LDS (BK=128), single barrier per K-tile, T14 issue-early staging.
__global__ __launch_bounds__(512) void e_kernel(const short* __restrict__ encb,
                                                const short* __restrict__ Wkb,
                                                const short* __restrict__ Wattb,
                                                const float* __restrict__ S,
                                                const float* __restrict__ Qb,
                                                const float* __restrict__ gw,
                                                const float* __restrict__ gb,
                                                const int* __restrict__ lens,
                                                float* __restrict__ ebuf) {
  __shared__ short At[2][64][136];   // +8 pad: 272B rows -> 2-way (free) on ds_read_b128
  __shared__ float epart[8][64];

  int bid = blockIdx.x;
  int h = bid >> 9; int rem = bid & 511; int b = rem >> 5; int t0 = (rem & 31) << 6;
  int tid = threadIdx.x; int w = tid >> 6; int l = tid & 63;
  int lrow = l & 15, lhi = l >> 4;
  int len = lens[b];
  float invlen = 1.0f / (float)len;
  int af = (100 * (h + 1)) >> 2;

  const short* encB = encb + ((size_t)(b * TT + t0)) * EPROJS;
  int srow = tid >> 3;               // staging row (0..63)
  int scol = (tid & 7) * 16;         // staging col start (shorts)

  // prolog: issue tile-0 global loads early
  bf16x8 s0, s1;
  {
    const short* src = encB + (size_t)srow * EPROJS + scol;
    s0 = *reinterpret_cast<const bf16x8*>(src);
    s1 = *reinterpret_cast<const bf16x8*>(src + 8);
  }

  // conv feature tile (cols 0..127) into At[0] via prefix sums
  const float* Sh = S + h * 202 * 128;
  for (int idx = tid; idx < 64 * 128; idx += 512) {
    int r = idx >> 7, c = idx & 127;
    int t = t0 + r;
    int lo = af - t; if (lo < 0) lo = 0;
    int hi = af - t + len - 1; if (hi > 2 * af) hi = 2 * af;
    float v = 0.f;
    if (hi >= lo) v = (Sh[(hi + 1) * 128 + c] - Sh[lo * 128 + c]) * invlen;
    At[0][r][c] = f2bf(v);
  }

  f32x4 acc[4][4] = {};
  const short* WkhB = Wkb + (size_t)h * DK * EPROJS;
  const short* WattB = Wattb + (size_t)h * DK * CCH;

  __syncthreads();   // conv tile visible

  // conv channels: 4 K-steps from At[0]
#pragma unroll
  for (int kk = 0; kk < 4; ++kk) {
    bf16x8 afr[4], bfr[4];
#pragma unroll
    for (int m = 0; m < 4; ++m)
      afr[m] = *reinterpret_cast<const bf16x8*>(&At[0][m * 16 + lrow][kk * 32 + lhi * 8]);
#pragma unroll
    for (int n = 0; n < 4; ++n) {
      int col = w * 64 + n * 16 + lrow;
      bfr[n] = *reinterpret_cast<const bf16x8*>(WattB + (size_t)col * CCH + kk * 32 + lhi * 8);
    }
#pragma unroll
    for (int m = 0; m < 4; ++m)
#pragma unroll
      for (int n = 0; n < 4; ++n)
        acc[m][n] = __builtin_amdgcn_mfma_f32_16x16x32_bf16(afr[m], bfr[n], acc[m][n], 0, 0, 0);
  }

  // write tile 0 into At[1] (safe: nobody reads At[1] until next barrier)
  {
    short* dst = &At[1][srow][scol];
    *reinterpret_cast<bf16x8*>(dst) = s0;
    *reinterpret_cast<bf16x8*>(dst + 8) = s1;
  }

  // main K loop: 8 tiles of BK=128, one barrier per tile
  for (int t = 0; t < 8; ++t) {
    int buf = (t + 1) & 1;           // tile t lives in this buffer
    if (t < 7) {
      const short* src = encB + (size_t)srow * EPROJS + (t + 1) * 128 + scol;
      s0 = *reinterpret_cast<const bf16x8*>(src);
      s1 = *reinterpret_cast<const bf16x8*>(src + 8);
    }
    __syncthreads();                 // tile t writes visible; prev-tile readers done
#pragma unroll
    for (int kk = 0; kk < 4; ++kk) {
      bf16x8 afr[4], bfr[4];
#pragma unroll
      for (int m = 0; m < 4; ++m)
        afr[m] = *reinterpret_cast<const bf16x8*>(&At[buf][m * 16 + lrow][kk * 32 + lhi * 8]);
#pragma unroll
      for (int n = 0; n < 4; ++n) {
        int col = w * 64 + n * 16 + lrow;
        bfr[n] = *reinterpret_cast<const bf16x8*>(WkhB + (size_t)col * EPROJS + t * 128 + kk * 32 + lhi * 8);
      }
#pragma unroll
      for (int m = 0; m < 4; ++m)
#pragma unroll
        for (int n = 0; n < 4; ++n)
          acc[m][n] = __builtin_amdgcn_mfma_f32_16x16x32_bf16(afr[m], bfr[n], acc[m][n], 0, 0, 0);
    }
    if (t < 7) {
      short* dst = &At[buf ^ 1][srow][scol];
      *reinterpret_cast<bf16x8*>(dst) = s0;
      *reinterpret_cast<bf16x8*>(dst + 8) = s1;
    }
  }

  // epilogue: tanh(pre + Q) * g_w, reduce over k
  float part[4][4];
#pragma unroll
  for (int m = 0; m < 4; ++m)
#pragma unroll
    for (int r = 0; r < 4; ++r) part[m][r] = 0.f;

#pragma unroll
  for (int n = 0; n < 4; ++n) {
    int col = w * 64 + n * 16 + lrow;
    float q = Qb[(h * BB + b) * DK + col];
    float g = gw[h * DK + col];
#pragma unroll
    for (int m = 0; m < 4; ++m)
#pragma unroll
      for (int r = 0; r < 4; ++r)
        part[m][r] += fast_tanh(acc[m][n][r] + q) * g;
  }
#pragma unroll
  for (int off = 1; off < 16; off <<= 1)
#pragma unroll
    for (int m = 0; m < 4; ++m)
#pragma unroll
      for (int r = 0; r < 4; ++r) part[m][r] += __shfl_xor(part[m][r], off);

  if (lrow == 0) {
#pragma unroll
    for (int m = 0; m < 4; ++m)
#pragma unroll
      for (int r = 0; r < 4; ++r) epart[w][m * 16 + lhi * 4 + r] = part[m][r];
  }
  __syncthreads();
  if (tid < 64) {
    float s = gb[h];
#pragma unroll
    for (int ww = 0; ww < 8; ++ww) s += epart[ww][tid];
    ebuf[(size_t)(h * BB + b) * TT + t0 + tid] = s;
  }
}

// ---------- masked softmax over t; writes ws region of d_out ----------
__global__ __launch_bounds__(256) void softmax_kernel(const float* __restrict__ ebuf,
                                                      const int* __restrict__ lens,
                                                      float* __restrict__ wout) {
  int hb = blockIdx.x; int b = hb & (BB - 1);
  int tid = threadIdx.x;
  int len = lens[b];
  const float scaling = 0.04419417382415922f;  // 1/sqrt(512)
  const float* er = ebuf + (size_t)hb * TT;
  float vals[8];
  float mx = -1e30f;
#pragma unroll
  for (int j = 0; j < 8; ++j) {
    int t = j * 256 + tid;
    float v = (t < len) ? scaling * er[t] : -1e30f;
    vals[j] = v; mx = fmaxf(mx, v);
  }
  __shared__ float red[256];
  red[tid] = mx; __syncthreads();
  for (int s2 = 128; s2; s2 >>= 1) { if (tid < s2) red[tid] = fmaxf(red[tid], red[tid + s2]); __syncthreads(); }
  mx = red[0]; __syncthreads();
  float sum = 0.f;
#pragma unroll
  for (int j = 0; j < 8; ++j) {
    int t = j * 256 + tid;
    vals[j] = (t < len) ? __expf(vals[j] - mx) : 0.f;
    sum += vals[j];
  }
  red[tid] = sum; __syncthreads();
  for (int s2 = 128; s2; s2 >>= 1) { if (tid < s2) red[tid] += red[tid + s2]; __syncthreads(); }
  float inv = 1.f / red[0];
#pragma unroll
  for (int j = 0; j < 8; ++j)
    wout[(size_t)hb * TT + j * 256 + tid] = vals[j] * inv;
}

__global__ __launch_bounds__(256) void zero_kernel(float* __restrict__ p, int n) {
  int i = blockIdx.x * blockDim.x + threadIdx.x;
  if (i < n) p[i] = 0.f;
}

// ---------- ctx[h][b][e] = sum_t w[h][b][t] * enc[b][t][e] ; enc read exactly once ----------
__global__ __launch_bounds__(256) void ctx_kernel(const float* __restrict__ enc,
                                                  const float* __restrict__ wout,
                                                  float* __restrict__ ctx) {
  int bid = blockIdx.x;                      // B * 4 * 8 = 512
  int tc = bid & 7; int ec = (bid >> 3) & 3; int b = bid >> 5;
  int tid = threadIdx.x;
  int ecol = ec * 256 + tid;
  int t0 = tc * 256;
  __shared__ float wls[4][256];
#pragma unroll
  for (int h = 0; h < 4; ++h) wls[h][tid] = wout[(size_t)(h * BB + b) * TT + t0 + tid];
  __syncthreads();
  float a0 = 0.f, a1 = 0.f, a2 = 0.f, a3 = 0.f;
  const float* ep = enc + ((size_t)(b * TT + t0)) * EPROJS + ecol;
  for (int t2 = 0; t2 < 256; ++t2) {
    float v = ep[(size_t)t2 * EPROJS];
    a0 += wls[0][t2] * v; a1 += wls[1][t2] * v; a2 += wls[2][t2] * v; a3 += wls[3][t2] * v;
  }
  atomicAdd(&ctx[(0 * BB + b) * EPROJS + ecol], a0);
  atomicAdd(&ctx[(1 * BB + b) * EPROJS + ecol], a1);
  atomicAdd(&ctx[(2 * BB + b) * EPROJS + ecol], a2);
  atomicAdd(&ctx[(3 * BB + b) * EPROJS + ecol], a3);
}

// ---------- cv[b][h*512+v] = ctx[h][b] . Wv[h][v] ----------
__global__ __launch_bounds__(256) void cv_kernel(const float* __restrict__ ctx,
                                                 const float* __restrict__ Wv,
                                                 float* __restrict__ cvb) {
  int wid = (blockIdx.x * blockDim.x + threadIdx.x) >> 6;
  int lane = threadIdx.x & 63;
  int v = wid & (DV - 1); int hb = wid >> 9; int b = hb & (BB - 1); int h = hb >> 4;
  const float4* c4 = reinterpret_cast<const float4*>(ctx + (size_t)(h * BB + b) * EPROJS);
  const float4* w4 = reinterpret_cast<const float4*>(Wv + (size_t)(h * DV + v) * EPROJS);
  float s = 0.f;
#pragma unroll
  for (int j = 0; j < 4; ++j) {
    float4 a = c4[j * 64 + lane], ww = w4[j * 64 + lane];
    s += a.x * ww.x + a.y * ww.y + a.z * ww.z + a.w * ww.w;
  }
#pragma unroll
  for (int off = 32; off; off >>= 1) s += __shfl_xor(s, off);
  if (lane == 0) cvb[b * 2048 + h * DV + v] = s;
}

// ---------- c[b][p] = cv[b] . Wo[p] ----------
__global__ __launch_bounds__(256) void out_kernel(const float* __restrict__ cvb,
                                                  const float* __restrict__ Wo,
                                                  float* __restrict__ outc) {
  int wid = (blockIdx.x * blockDim.x + threadIdx.x) >> 6;
  int lane = threadIdx.x & 63;
  int p = wid & 1023; int b = wid >> 10;
  const float4* a4 = reinterpret_cast<const float4*>(cvb + (size_t)b * 2048);
  const float4* w4 = reinterpret_cast<const float4*>(Wo + (size_t)p * 2048);
  float s = 0.f;
#pragma unroll
  for (int j = 0; j < 8; ++j) {
    float4 a = a4[j * 64 + lane], ww = w4[j * 64 + lane];
    s += a.x * ww.x + a.y * ww.y + a.z * ww.z + a.w * ww.w;
  }
#pragma unroll
  for (int off = 32; off; off >>= 1) s += __shfl_xor(s, off);
  if (lane == 0) outc[b * 1024 + p] = s;
}

extern "C" void kernel_launch(void* const* d_in, const int* in_sizes, int n_in,
                              void* d_out, int out_size, void* d_ws, size_t ws_size,
                              hipStream_t stream) {
  const float* enc  = (const float*)d_in[0];
  const int*   lens = (const int*)d_in[1];
  const float* dec  = (const float*)d_in[2];
  const float* Wq   = (const float*)d_in[3];
  const float* bq   = (const float*)d_in[4];
  const float* Wk   = (const float*)d_in[5];
  const float* Wv   = (const float*)d_in[6];
  const float* gw   = (const float*)d_in[7];
  const float* gb   = (const float*)d_in[8];
  const float* Watt = (const float*)d_in[9];
  const float* cw0  = (const float*)d_in[10];
  const float* cw1  = (const float*)d_in[11];
  const float* cw2  = (const float*)d_in[12];
  const float* cw3  = (const float*)d_in[13];
  const float* Wo   = (const float*)d_in[14];
  float* out = (float*)d_out;

  char* ws = (char*)d_ws;
  short* Wkb   = (short*)(ws);                 // 4 MiB
  short* Wattb = (short*)(ws + 4194304);       // 512 KiB
  float* S     = (float*)(ws + 4718592);       // 404 KiB
  float* Qb    = (float*)(ws + 5132288);       // 128 KiB
  float* ebuf  = (float*)(ws + 5263360);       // 512 KiB
  float* ctx   = (float*)(ws + 5787648);       // 256 KiB
  float* cvb   = (float*)(ws + 6049792);       // 128 KiB
  short* encb  = (short*)(ws + 6291456);       // 64 MiB bf16 enc

  float* wsout = out + 16384;                  // ws output region (4,16,2048)

  cvt_kernel<<<32768, 256, 0, stream>>>(enc, encb, 8388608);
  cvt_kernel<<<2048, 256, 0, stream>>>(Wk, Wkb, 524288);
  cvt_kernel<<<256, 256, 0, stream>>>(Watt, Wattb, 65536);
  prefix_kernel<<<4, 128, 0, stream>>>(cw0, cw1, cw2, cw3, S);
  q_kernel<<<8192, 256, 0, stream>>>(dec, Wq, bq, Qb);
  zero_kernel<<<256, 256, 0, stream>>>(ctx, 65536);
  e_kernel<<<2048, 512, 0, stream>>>(encb, Wkb, Wattb, S, Qb, gw, gb, lens, ebuf);
  softmax_kernel<<<64, 256, 0, stream>>>(ebuf, lens, wsout);
  ctx_kernel<<<512, 256, 0, stream>>>(enc, wsout, ctx);
  cv_kernel<<<8192, 256, 0, stream>>>(ctx, Wv, cvb);
  out_kernel<<<4096, 256, 0, stream>>>(cvb, Wo, out);
}

// Round 3
// 356.532 us; speedup vs baseline: 1.2783x; 1.2783x over previous
//
#include <hip/hip_runtime.h>

#define EPROJS 1024
#define DUNITS 1024
#define AHEADS 4
#define DK 512
#define DV 512
#define CCH 128
#define BB 16
#define TT 2048

typedef __attribute__((ext_vector_type(8))) short bf16x8;
typedef __attribute__((ext_vector_type(4))) float f32x4;

static __device__ __forceinline__ short f2bf(float x) {
  unsigned u = __float_as_uint(x);
  unsigned r = u + 0x7fffu + ((u >> 16) & 1u);   // RNE to bf16 (inputs finite)
  return (short)(r >> 16);
}
static __device__ __forceinline__ float bf2f(short x) {
  return __uint_as_float(((unsigned)(unsigned short)x) << 16);
}

static __device__ __forceinline__ float fast_tanh(float x) {
  float e2 = __expf(2.0f * x);
  return 1.0f - 2.0f / (e2 + 1.0f);
}

// ---------- f32 -> bf16 conversion (vector of 4) ----------
__global__ __launch_bounds__(256) void cvt_kernel(const float* __restrict__ in,
                                                  short* __restrict__ out, int n4) {
  int i = blockIdx.x * blockDim.x + threadIdx.x;
  if (i >= n4) return;
  float4 v = reinterpret_cast<const float4*>(in)[i];
  short4 o;
  o.x = f2bf(v.x); o.y = f2bf(v.y); o.z = f2bf(v.z); o.w = f2bf(v.w);
  reinterpret_cast<short4*>(out)[i] = o;
}

// ---------- pack B = [Wk | Watt] into MFMA fragment order ----------
// Bp[h][kkidx(36)][nblk(32)][lane(64)][8]; kkidx<32 -> Wk (k=kkidx*32), else Watt.
__global__ __launch_bounds__(256) void packB_kernel(const float* __restrict__ Wk,
                                                    const float* __restrict__ Watt,
                                                    short* __restrict__ Bp) {
  int idx = blockIdx.x * 256 + threadIdx.x;          // 4*36*32*64 = 294912
  if (idx >= 294912) return;
  int lane = idx & 63; int t = idx >> 6;
  int nblk = t & 31; t >>= 5;
  int kkidx = t % 36; int h = t / 36;
  int col = nblk * 16 + (lane & 15);
  int k0 = kkidx * 32 + (lane >> 4) * 8;
  const float* src;
  if (k0 < 1024) src = Wk + ((size_t)(h * DK + col)) * EPROJS + k0;
  else           src = Watt + ((size_t)(h * DK + col)) * CCH + (k0 - 1024);
  float4 v0 = reinterpret_cast<const float4*>(src)[0];
  float4 v1 = reinterpret_cast<const float4*>(src)[1];
  short o[8] = { f2bf(v0.x), f2bf(v0.y), f2bf(v0.z), f2bf(v0.w),
                 f2bf(v1.x), f2bf(v1.y), f2bf(v1.z), f2bf(v1.w) };
  *reinterpret_cast<bf16x8*>(Bp + (size_t)idx * 8) = *reinterpret_cast<bf16x8*>(o);
}

// ---------- filter prefix sums: S[h][tau][c], tau in [0, L] ----------
__global__ __launch_bounds__(128) void prefix_kernel(const float* __restrict__ w0,
                                                     const float* __restrict__ w1,
                                                     const float* __restrict__ w2,
                                                     const float* __restrict__ w3,
                                                     float* __restrict__ S) {
  int h = blockIdx.x, c = threadIdx.x;
  const float* wk = (h == 0) ? w0 : (h == 1) ? w1 : (h == 2) ? w2 : w3;
  int af = (100 * (h + 1)) >> 2;
  int L = 2 * af + 1;
  float* Sh = S + h * 202 * 128;
  float s = 0.f;
  Sh[c] = 0.f;
  for (int t = 0; t < L; ++t) { s += wk[c * L + t]; Sh[(t + 1) * 128 + c] = s; }
}

// ---------- Q[h][b][k] ----------
__global__ __launch_bounds__(256) void q_kernel(const float* __restrict__ dec,
                                                const float* __restrict__ Wq,
                                                const float* __restrict__ bq,
                                                float* __restrict__ Qb) {
  int wid = (blockIdx.x * blockDim.x + threadIdx.x) >> 6;
  int lane = threadIdx.x & 63;
  int k = wid & (DK - 1); int hb = wid >> 9; int b = hb & (BB - 1); int h = hb >> 4;
  const float4* d4 = reinterpret_cast<const float4*>(dec + b * DUNITS);
  const float4* w4 = reinterpret_cast<const float4*>(Wq + (size_t)(h * DK + k) * DUNITS);
  float s = 0.f;
#pragma unroll
  for (int j = 0; j < 4; ++j) {
    float4 a = d4[j * 64 + lane], w = w4[j * 64 + lane];
    s += a.x * w.x + a.y * w.y + a.z * w.z + a.w * w.w;
  }
#pragma unroll
  for (int off = 32; off; off >>= 1) s += __shfl_xor(s, off);
  if (lane == 0) Qb[wid] = s + bq[h * DK + k];
}

// ---------- fused e kernel ----------
// A tiles in XOR-swizzled linear LDS [64][128] (chunk ^= row&7); B from packed Bp
// with wave-contiguous 1KB loads + one-kk-ahead register prefetch.
__global__ __launch_bounds__(512, 3) void e_kernel(const short* __restrict__ encb,
                                                   const short* __restrict__ Bp,
                                                   const float* __restrict__ S,
                                                   const float* __restrict__ Qb,
                                                   const float* __restrict__ gw,
                                                   const float* __restrict__ gb,
                                                   const int* __restrict__ lens,
                                                   float* __restrict__ ebuf) {
  __shared__ short At[2][64 * 128];
  __shared__ short Ac[64 * 128];
  __shared__ float epart[8][64];

  int bid = blockIdx.x;
  int h = bid >> 9; int rem = bid & 511; int b = rem >> 5; int t0 = (rem & 31) << 6;
  int tid = threadIdx.x; int w = tid >> 6; int l = tid & 63;
  int lrow = l & 15, lhi = l >> 4;
  int len = lens[b];
  float invlen = 1.0f / (float)len;
  int af = (100 * (h + 1)) >> 2;

  const short* encB = encb + ((size_t)(b * TT + t0)) * EPROJS;
  const short* BpH = Bp + (size_t)h * 36 * 32 * 64 * 8;

  // staging: thread covers chunks sc and sc+8 of row srow
  int srow = tid >> 3;
  int sc = tid & 7;
  int wo0 = srow * 128 + ((sc ^ (srow & 7)) << 3);
  int wo1 = srow * 128 + (((sc + 8) ^ (srow & 7)) << 3);
  const short* sbase = encB + (size_t)srow * EPROJS + sc * 8;

  // read-side swizzle: afr[m] at row m*16+lrow, chunk kk*4+lhi -> XOR with lrow&7
  int rx = lrow & 7;

  // prolog: issue tile-0 global loads
  bf16x8 s0 = *reinterpret_cast<const bf16x8*>(sbase);
  bf16x8 s1 = *reinterpret_cast<const bf16x8*>(sbase + 64);

  // conv feature tile into Ac (swizzled)
  const float* Sh = S + h * 202 * 128;
  for (int idx = tid; idx < 64 * 128; idx += 512) {
    int r = idx >> 7, c = idx & 127;
    int t = t0 + r;
    int lo = af - t; if (lo < 0) lo = 0;
    int hi = af - t + len - 1; if (hi > 2 * af) hi = 2 * af;
    float v = 0.f;
    if (hi >= lo) v = (Sh[(hi + 1) * 128 + c] - Sh[lo * 128 + c]) * invlen;
    Ac[r * 128 + (((c >> 3) ^ (r & 7)) << 3) + (c & 7)] = f2bf(v);
  }

  f32x4 acc[4][4] = {};

  // prefetch conv B kk=0
  bf16x8 bnext[4];
#pragma unroll
  for (int n = 0; n < 4; ++n)
    bnext[n] = *reinterpret_cast<const bf16x8*>(BpH + (((size_t)32 * 32 + (w * 4 + n)) * 64 + l) * 8);

  __syncthreads();   // conv tile visible

  // conv channels: kkidx 32..35 from Ac
#pragma unroll
  for (int kk = 0; kk < 4; ++kk) {
    bf16x8 bcur[4];
#pragma unroll
    for (int n = 0; n < 4; ++n) bcur[n] = bnext[n];
    int nk = (kk < 3) ? (33 + kk) : 0;   // after conv, prefetch main kkidx 0
#pragma unroll
    for (int n = 0; n < 4; ++n)
      bnext[n] = *reinterpret_cast<const bf16x8*>(BpH + (((size_t)nk * 32 + (w * 4 + n)) * 64 + l) * 8);
    bf16x8 afr[4];
    int x = (kk * 4 + lhi) ^ rx;
#pragma unroll
    for (int m = 0; m < 4; ++m)
      afr[m] = *reinterpret_cast<const bf16x8*>(&Ac[(m * 16 + lrow) * 128 + x * 8]);
#pragma unroll
    for (int m = 0; m < 4; ++m)
#pragma unroll
      for (int n = 0; n < 4; ++n)
        acc[m][n] = __builtin_amdgcn_mfma_f32_16x16x32_bf16(afr[m], bcur[n], acc[m][n], 0, 0, 0);
  }

  // write tile 0 into At[0] (read at tl=0 after next barrier)
  *reinterpret_cast<bf16x8*>(&At[0][wo0]) = s0;
  *reinterpret_cast<bf16x8*>(&At[0][wo1]) = s1;

  // main K loop: 8 tiles of BK=128, one barrier per tile
  for (int tl = 0; tl < 8; ++tl) {
    int buf = tl & 1;
    if (tl < 7) {
      s0 = *reinterpret_cast<const bf16x8*>(sbase + (tl + 1) * 128);
      s1 = *reinterpret_cast<const bf16x8*>(sbase + (tl + 1) * 128 + 64);
    }
    __syncthreads();
#pragma unroll
    for (int kk = 0; kk < 4; ++kk) {
      bf16x8 bcur[4];
#pragma unroll
      for (int n = 0; n < 4; ++n) bcur[n] = bnext[n];
      int nk = tl * 4 + kk + 1;
      if (nk < 32) {
#pragma unroll
        for (int n = 0; n < 4; ++n)
          bnext[n] = *reinterpret_cast<const bf16x8*>(BpH + (((size_t)nk * 32 + (w * 4 + n)) * 64 + l) * 8);
      }
      bf16x8 afr[4];
      int x = (kk * 4 + lhi) ^ rx;
#pragma unroll
      for (int m = 0; m < 4; ++m)
        afr[m] = *reinterpret_cast<const bf16x8*>(&At[buf][(m * 16 + lrow) * 128 + x * 8]);
#pragma unroll
      for (int m = 0; m < 4; ++m)
#pragma unroll
        for (int n = 0; n < 4; ++n)
          acc[m][n] = __builtin_amdgcn_mfma_f32_16x16x32_bf16(afr[m], bcur[n], acc[m][n], 0, 0, 0);
    }
    if (tl < 7) {
      *reinterpret_cast<bf16x8*>(&At[buf ^ 1][wo0]) = s0;
      *reinterpret_cast<bf16x8*>(&At[buf ^ 1][wo1]) = s1;
    }
  }

  // epilogue: tanh(pre + Q) * g_w, reduce over k
  float part[4][4];
#pragma unroll
  for (int m = 0; m < 4; ++m)
#pragma unroll
    for (int r = 0; r < 4; ++r) part[m][r] = 0.f;

#pragma unroll
  for (int n = 0; n < 4; ++n) {
    int col = w * 64 + n * 16 + lrow;
    float q = Qb[(h * BB + b) * DK + col];
    float g = gw[h * DK + col];
#pragma unroll
    for (int m = 0; m < 4; ++m)
#pragma unroll
      for (int r = 0; r < 4; ++r)
        part[m][r] += fast_tanh(acc[m][n][r] + q) * g;
  }
#pragma unroll
  for (int off = 1; off < 16; off <<= 1)
#pragma unroll
    for (int m = 0; m < 4; ++m)
#pragma unroll
      for (int r = 0; r < 4; ++r) part[m][r] += __shfl_xor(part[m][r], off);

  if (lrow == 0) {
#pragma unroll
    for (int m = 0; m < 4; ++m)
#pragma unroll
      for (int r = 0; r < 4; ++r) epart[w][m * 16 + lhi * 4 + r] = part[m][r];
  }
  __syncthreads();
  if (tid < 64) {
    float s = gb[h];
#pragma unroll
    for (int ww = 0; ww < 8; ++ww) s += epart[ww][tid];
    ebuf[(size_t)(h * BB + b) * TT + t0 + tid] = s;
  }
}

// ---------- masked softmax over t; writes ws region of d_out ----------
__global__ __launch_bounds__(256) void softmax_kernel(const float* __restrict__ ebuf,
                                                      const int* __restrict__ lens,
                                                      float* __restrict__ wout) {
  int hb = blockIdx.x; int b = hb & (BB - 1);
  int tid = threadIdx.x;
  int len = lens[b];
  const float scaling = 0.04419417382415922f;  // 1/sqrt(512)
  const float* er = ebuf + (size_t)hb * TT;
  float vals[8];
  float mx = -1e30f;
#pragma unroll
  for (int j = 0; j < 8; ++j) {
    int t = j * 256 + tid;
    float v = (t < len) ? scaling * er[t] : -1e30f;
    vals[j] = v; mx = fmaxf(mx, v);
  }
  __shared__ float red[256];
  red[tid] = mx; __syncthreads();
  for (int s2 = 128; s2; s2 >>= 1) { if (tid < s2) red[tid] = fmaxf(red[tid], red[tid + s2]); __syncthreads(); }
  mx = red[0]; __syncthreads();
  float sum = 0.f;
#pragma unroll
  for (int j = 0; j < 8; ++j) {
    int t = j * 256 + tid;
    vals[j] = (t < len) ? __expf(vals[j] - mx) : 0.f;
    sum += vals[j];
  }
  red[tid] = sum; __syncthreads();
  for (int s2 = 128; s2; s2 >>= 1) { if (tid < s2) red[tid] += red[tid + s2]; __syncthreads(); }
  float inv = 1.f / red[0];
#pragma unroll
  for (int j = 0; j < 8; ++j)
    wout[(size_t)hb * TT + j * 256 + tid] = vals[j] * inv;
}

__global__ __launch_bounds__(256) void zero_kernel(float* __restrict__ p, int n) {
  int i = blockIdx.x * blockDim.x + threadIdx.x;
  if (i < n) p[i] = 0.f;
}

// ---------- ctx[h][b][e] = sum_t w[h][b][t] * enc_bf16[b][t][e] ----------
__global__ __launch_bounds__(256) void ctx_kernel(const short* __restrict__ encb,
                                                  const float* __restrict__ wout,
                                                  float* __restrict__ ctx) {
  int bid = blockIdx.x;                      // 16 * 4 * 8 = 512
  int tc = bid & 7; int ec = (bid >> 3) & 3; int b = bid >> 5;
  int tid = threadIdx.x;
  int ecol = ec * 256 + tid;
  int t0 = tc * 256;
  __shared__ float wls[4][256];
#pragma unroll
  for (int h = 0; h < 4; ++h) wls[h][tid] = wout[(size_t)(h * BB + b) * TT + t0 + tid];
  __syncthreads();
  float a0 = 0.f, a1 = 0.f, a2 = 0.f, a3 = 0.f;
  const short* ep = encb + ((size_t)(b * TT + t0)) * EPROJS + ecol;
  for (int t2 = 0; t2 < 256; ++t2) {
    float v = bf2f(ep[(size_t)t2 * EPROJS]);
    a0 += wls[0][t2] * v; a1 += wls[1][t2] * v; a2 += wls[2][t2] * v; a3 += wls[3][t2] * v;
  }
  atomicAdd(&ctx[(0 * BB + b) * EPROJS + ecol], a0);
  atomicAdd(&ctx[(1 * BB + b) * EPROJS + ecol], a1);
  atomicAdd(&ctx[(2 * BB + b) * EPROJS + ecol], a2);
  atomicAdd(&ctx[(3 * BB + b) * EPROJS + ecol], a3);
}

// ---------- cv[b][h*512+v] = ctx[h][b] . Wv[h][v] ; one wave per (h,v), all 16 b ----------
__global__ __launch_bounds__(256) void cv_kernel(const float* __restrict__ ctx,
                                                 const float* __restrict__ Wv,
                                                 float* __restrict__ cvb) {
  int wid = (blockIdx.x * blockDim.x + threadIdx.x) >> 6;   // 0..2047
  int lane = threadIdx.x & 63;
  int v = wid & (DV - 1); int h = wid >> 9;
  const float4* w4 = reinterpret_cast<const float4*>(Wv + (size_t)(h * DV + v) * EPROJS);
  float acc[BB];
#pragma unroll
  for (int b = 0; b < BB; ++b) acc[b] = 0.f;
#pragma unroll
  for (int j = 0; j < 4; ++j) {
    float4 ww = w4[j * 64 + lane];
#pragma unroll
    for (int b = 0; b < BB; ++b) {
      float4 a = reinterpret_cast<const float4*>(ctx + (size_t)(h * BB + b) * EPROJS)[j * 64 + lane];
      acc[b] += a.x * ww.x + a.y * ww.y + a.z * ww.z + a.w * ww.w;
    }
  }
#pragma unroll
  for (int off = 32; off; off >>= 1)
#pragma unroll
    for (int b = 0; b < BB; ++b) acc[b] += __shfl_xor(acc[b], off);
  if (lane == 0) {
#pragma unroll
    for (int b = 0; b < BB; ++b) cvb[b * 2048 + h * DV + v] = acc[b];
  }
}

// ---------- c[b][p] = cv[b] . Wo[p] ; one wave per p, all 16 b ----------
__global__ __launch_bounds__(256) void out_kernel(const float* __restrict__ cvb,
                                                  const float* __restrict__ Wo,
                                                  float* __restrict__ outc) {
  int p = (blockIdx.x * blockDim.x + threadIdx.x) >> 6;   // 0..1023
  int lane = threadIdx.x & 63;
  const float4* w4 = reinterpret_cast<const float4*>(Wo + (size_t)p * 2048);
  float acc[BB];
#pragma unroll
  for (int b = 0; b < BB; ++b) acc[b] = 0.f;
#pragma unroll
  for (int j = 0; j < 8; ++j) {
    float4 ww = w4[j * 64 + lane];
#pragma unroll
    for (int b = 0; b < BB; ++b) {
      float4 a = reinterpret_cast<const float4*>(cvb + (size_t)b * 2048)[j * 64 + lane];
      acc[b] += a.x * ww.x + a.y * ww.y + a.z * ww.z + a.w * ww.w;
    }
  }
#pragma unroll
  for (int off = 32; off; off >>= 1)
#pragma unroll
    for (int b = 0; b < BB; ++b) acc[b] += __shfl_xor(acc[b], off);
  if (lane == 0) {
#pragma unroll
    for (int b = 0; b < BB; ++b) outc[b * 1024 + p] = acc[b];
  }
}

extern "C" void kernel_launch(void* const* d_in, const int* in_sizes, int n_in,
                              void* d_out, int out_size, void* d_ws, size_t ws_size,
                              hipStream_t stream) {
  const float* enc  = (const float*)d_in[0];
  const int*   lens = (const int*)d_in[1];
  const float* dec  = (const float*)d_in[2];
  const float* Wq   = (const float*)d_in[3];
  const float* bq   = (const float*)d_in[4];
  const float* Wk   = (const float*)d_in[5];
  const float* Wv   = (const float*)d_in[6];
  const float* gw   = (const float*)d_in[7];
  const float* gb   = (const float*)d_in[8];
  const float* Watt = (const float*)d_in[9];
  const float* cw0  = (const float*)d_in[10];
  const float* cw1  = (const float*)d_in[11];
  const float* cw2  = (const float*)d_in[12];
  const float* cw3  = (const float*)d_in[13];
  const float* Wo   = (const float*)d_in[14];
  float* out = (float*)d_out;

  char* ws = (char*)d_ws;
  short* Bp    = (short*)(ws);                 // 4,718,592 B
  float* S     = (float*)(ws + 4718592);       // 413,696 B
  float* Qb    = (float*)(ws + 5132288);       // 131,072 B
  float* ebuf  = (float*)(ws + 5263360);       // 524,288 B
  float* ctx   = (float*)(ws + 5787648);       // 262,144 B
  float* cvb   = (float*)(ws + 6049792);       // 131,072 B
  short* encb  = (short*)(ws + 6291456);       // 67,108,864 B

  float* wsout = out + 16384;                  // ws output region (4,16,2048)

  cvt_kernel<<<32768, 256, 0, stream>>>(enc, encb, 8388608);
  packB_kernel<<<1152, 256, 0, stream>>>(Wk, Watt, Bp);
  prefix_kernel<<<4, 128, 0, stream>>>(cw0, cw1, cw2, cw3, S);
  q_kernel<<<8192, 256, 0, stream>>>(dec, Wq, bq, Qb);
  zero_kernel<<<256, 256, 0, stream>>>(ctx, 65536);
  e_kernel<<<2048, 512, 0, stream>>>(encb, Bp, S, Qb, gw, gb, lens, ebuf);
  softmax_kernel<<<64, 256, 0, stream>>>(ebuf, lens, wsout);
  ctx_kernel<<<512, 256, 0, stream>>>(encb, wsout, ctx);
  cv_kernel<<<512, 256, 0, stream>>>(ctx, Wv, cvb);
  out_kernel<<<256, 256, 0, stream>>>(cvb, Wo, out);
}